// Round 4
// baseline (2587.283 us; speedup 1.0000x reference)
//
#include <hip/hip_runtime.h>
#include <hip/hip_fp16.h>

typedef unsigned int u32;
typedef _Float16 half2v __attribute__((ext_vector_type(2)));
typedef _Float16 half4v __attribute__((ext_vector_type(4)));
typedef _Float16 half8v __attribute__((ext_vector_type(8)));
typedef float f32x4 __attribute__((ext_vector_type(4)));

#define T_DIM 1024
#define B_DIM 256
#define H_DIM 256
#define G_DIM 768   // 3*H

// ---------------------------------------------------------------------------
// prep: transpose + f32->f16 for both weight matrices.
// WiT/WhT[g][k] = W[k][g]  (g in [0,768), k in [0,256))
// ---------------------------------------------------------------------------
__global__ void prep_kernel(const float* __restrict__ Wi,
                            const float* __restrict__ Wh,
                            _Float16* __restrict__ WiT,
                            _Float16* __restrict__ WhT) {
  int idx = blockIdx.x * 256 + threadIdx.x;
  const int total = G_DIM * H_DIM;
  const float* src = Wi;
  _Float16* dst = WiT;
  if (idx >= total) { idx -= total; src = Wh; dst = WhT; }
  int g = idx >> 8;     // 0..767
  int k = idx & 255;    // 0..255
  dst[idx] = (_Float16)src[(size_t)k * G_DIM + g];
}

// ---------------------------------------------------------------------------
// Phase 1: gi[M][768] (f16) = ins[M][256] (f32) @ Wi + bi, via MFMA f16.
// (unchanged; secondary target)
// ---------------------------------------------------------------------------
#define BM 128
#define BN 128
#define BK 64
#define LDK 72   // padded f16 leading dim

__global__ __launch_bounds__(256, 2) void gemm_gi_kernel(
    const float* __restrict__ A,       // ins [M][256]
    const _Float16* __restrict__ BT,   // WiT [768][256]
    const float* __restrict__ bias,    // bi [768] f32
    _Float16* __restrict__ C)          // gi [M][768]
{
  __shared__ _Float16 As[BM * LDK];
  __shared__ _Float16 Bs[BN * LDK];

  const int tid  = threadIdx.x;
  const int lane = tid & 63;
  const int wid  = tid >> 6;
  const int wr   = wid >> 1;
  const int wc   = wid & 1;

  const int id   = blockIdx.x;
  const int xcd  = id & 7;
  const int slot = id >> 3;
  const int nt   = slot % 6;
  const int mt   = (slot / 6) * 8 + xcd;
  const int m0 = mt * BM;
  const int n0 = nt * BN;

  f32x4 acc[4][4] = {};

  for (int kt = 0; kt < H_DIM; kt += BK) {
#pragma unroll
    for (int i = 0; i < 8; ++i) {
      int c   = tid + i * 256;
      int row = c >> 4;
      int kc  = (c & 15) << 2;
      const float4 v = *(const float4*)(A + (size_t)(m0 + row) * H_DIM + kt + kc);
      half4v h;
      h.x = (_Float16)v.x; h.y = (_Float16)v.y;
      h.z = (_Float16)v.z; h.w = (_Float16)v.w;
      *(half4v*)(&As[row * LDK + kc]) = h;
    }
#pragma unroll
    for (int i = 0; i < 8; ++i) {
      int c   = tid + i * 256;
      int row = c >> 4;
      int kc  = (c & 15) << 2;
      half4v v = *(const half4v*)(BT + (size_t)(n0 + row) * H_DIM + kt + kc);
      *(half4v*)(&Bs[row * LDK + kc]) = v;
    }
    __syncthreads();

#pragma unroll
    for (int kk = 0; kk < 2; ++kk) {
      half8v af[4], bf[4];
#pragma unroll
      for (int m = 0; m < 4; ++m)
        af[m] = *(const half8v*)(&As[(wr*64 + m*16 + (lane & 15)) * LDK + kk*32 + (lane >> 4)*8]);
#pragma unroll
      for (int n = 0; n < 4; ++n)
        bf[n] = *(const half8v*)(&Bs[(wc*64 + n*16 + (lane & 15)) * LDK + kk*32 + (lane >> 4)*8]);
#pragma unroll
      for (int m = 0; m < 4; ++m)
#pragma unroll
        for (int n = 0; n < 4; ++n)
          acc[m][n] = __builtin_amdgcn_mfma_f32_16x16x32_f16(af[m], bf[n], acc[m][n], 0, 0, 0);
    }
    __syncthreads();
  }

#pragma unroll
  for (int n = 0; n < 4; ++n) {
    const int col = n0 + wc*64 + n*16 + (lane & 15);
    const float bv = bias[col];
#pragma unroll
    for (int m = 0; m < 4; ++m) {
#pragma unroll
      for (int q = 0; q < 4; ++q) {
        const int row = m0 + wr*64 + m*16 + (lane >> 4)*4 + q;
        C[(size_t)row * G_DIM + col] = (_Float16)(acc[m][n][q] + bv);
      }
    }
  }
}

// ---------------------------------------------------------------------------
// Phase 2: MFMA-based persistent GRU scan.
// 256 blocks (1 chain each) x 256 threads (4 waves, 1 wave/SIMD).
// Wave w owns outputs j in [64w, 64w+64): 12 B-tiles (3 gates x 4 col-tiles)
// x 8 k-slices = 96 persistent B-frags (384 regs; MFMA reads AGPR natively,
// so no accvgpr_read tax — the fix for round 3's VALU bloat).
// A-frag trick: every lane loads the same h k-slice for its lane group
// (16*lg bytes), so ALL 16 rows of A equal h -> every row of D is gh, and
// the epilogue reads acc[g][q][0] with r/z/n in-lane (no cross-lane ops).
// Per step: 8 conflict-free ds_read_b128, 96 MFMA, ~100 VALU, 1 barrier.
// ---------------------------------------------------------------------------
__device__ __forceinline__ float sigmoidf_fast(float x) {
  return __builtin_amdgcn_rcpf(1.f + __expf(-x));
}
__device__ __forceinline__ float tanhf_fast(float x) {
  return 1.f - 2.f * __builtin_amdgcn_rcpf(__expf(2.f * x) + 1.f);
}

__global__ __launch_bounds__(256, 1) void gru_scan_kernel(
    const _Float16* __restrict__ WhT,   // [768][256]
    const _Float16* __restrict__ gi,    // [T][B][768] f16
    const int* __restrict__ resets,     // [T][B] int32
    const float* __restrict__ h0,       // [B][256]
    const float* __restrict__ bhn,      // [256]
    float* __restrict__ ys)             // [T][B][256]
{
  const int b   = blockIdx.x;
  const int tid = threadIdx.x;   // 0..255
  const int w   = tid >> 6;      // wave 0..3
  const int l   = tid & 63;
  const int lg  = l >> 4;        // lane group 0..3 (k sub-slice)
  const int lc  = l & 15;        // col within tile

  __shared__ __align__(16) _Float16 hbuf[2][H_DIM];

  // ---- persistent B fragments: wB[gate][coltile][kslice] ----
  // col = 256*g + 64*w + 16*q + lc ; k = 32*s + 8*lg + [0..7]
  half8v wB[3][4][8];
#pragma unroll
  for (int g = 0; g < 3; ++g)
#pragma unroll
    for (int q = 0; q < 4; ++q) {
      const _Float16* bp = WhT + (size_t)(256*g + 64*w + 16*q + lc) * H_DIM + 8*lg;
#pragma unroll
      for (int s = 0; s < 8; ++s)
        wB[g][q][s] = *(const half8v*)(bp + 32*s);
    }

  float bnq[4];
#pragma unroll
  for (int q = 0; q < 4; ++q) bnq[q] = bhn[64*w + 16*q + lc];

  // ---- init carry (masked by resets[0]) ----
  float hprev[4];
  {
    const int r0 = resets[b];
    const float* hp = h0 + (size_t)b * H_DIM;
#pragma unroll
    for (int q = 0; q < 4; ++q)
      hprev[q] = r0 ? 0.f : hp[64*w + 16*q + lc];
    hbuf[0][tid] = (_Float16)(r0 ? 0.f : hp[tid]);
  }
  __syncthreads();

  const _Float16* gbase = gi + (size_t)b * G_DIM;
  float* yb = ys + (size_t)b * H_DIM;

  // preload gi for t=0
  float gcur[12];
#pragma unroll
  for (int g = 0; g < 3; ++g)
#pragma unroll
    for (int q = 0; q < 4; ++q)
      gcur[g*4+q] = (float)gbase[256*g + 64*w + 16*q + lc];

  const f32x4 zero4 = {0.f, 0.f, 0.f, 0.f};

  int p = 0;
  for (int t = 0; t < T_DIM; ++t) {
    const char* hb = (const char*)(&hbuf[p][0]);

    // ---- phase 1: k-slices 0..3 ----
    half8v a0 = *(const half8v*)(hb +       16*lg);
    half8v a1 = *(const half8v*)(hb +  64 + 16*lg);
    half8v a2 = *(const half8v*)(hb + 128 + 16*lg);
    half8v a3 = *(const half8v*)(hb + 192 + 16*lg);

    f32x4 acc[3][4];
#pragma unroll
    for (int g = 0; g < 3; ++g)
#pragma unroll
      for (int q = 0; q < 4; ++q)
        acc[g][q] = __builtin_amdgcn_mfma_f32_16x16x32_f16(a0, wB[g][q][0], zero4, 0, 0, 0);
#pragma unroll
    for (int g = 0; g < 3; ++g)
#pragma unroll
      for (int q = 0; q < 4; ++q)
        acc[g][q] = __builtin_amdgcn_mfma_f32_16x16x32_f16(a1, wB[g][q][1], acc[g][q], 0, 0, 0);
#pragma unroll
    for (int g = 0; g < 3; ++g)
#pragma unroll
      for (int q = 0; q < 4; ++q)
        acc[g][q] = __builtin_amdgcn_mfma_f32_16x16x32_f16(a2, wB[g][q][2], acc[g][q], 0, 0, 0);
#pragma unroll
    for (int g = 0; g < 3; ++g)
#pragma unroll
      for (int q = 0; q < 4; ++q)
        acc[g][q] = __builtin_amdgcn_mfma_f32_16x16x32_f16(a3, wB[g][q][3], acc[g][q], 0, 0, 0);

    // ---- phase 2 loads + next-step prefetch (issue under MFMA shadow) ----
    half8v a4 = *(const half8v*)(hb + 256 + 16*lg);
    half8v a5 = *(const half8v*)(hb + 320 + 16*lg);
    half8v a6 = *(const half8v*)(hb + 384 + 16*lg);
    half8v a7 = *(const half8v*)(hb + 448 + 16*lg);

    const int rstn = (t + 1 < T_DIM) ? resets[(t + 1) * B_DIM + b] : 0;
    float gnxt[12];
    if (t + 1 < T_DIM) {
      const _Float16* gp = gbase + (size_t)(t + 1) * (B_DIM * G_DIM);
#pragma unroll
      for (int g = 0; g < 3; ++g)
#pragma unroll
        for (int q = 0; q < 4; ++q)
          gnxt[g*4+q] = (float)gp[256*g + 64*w + 16*q + lc];
    } else {
#pragma unroll
      for (int i = 0; i < 12; ++i) gnxt[i] = 0.f;
    }

#pragma unroll
    for (int g = 0; g < 3; ++g)
#pragma unroll
      for (int q = 0; q < 4; ++q)
        acc[g][q] = __builtin_amdgcn_mfma_f32_16x16x32_f16(a4, wB[g][q][4], acc[g][q], 0, 0, 0);
#pragma unroll
    for (int g = 0; g < 3; ++g)
#pragma unroll
      for (int q = 0; q < 4; ++q)
        acc[g][q] = __builtin_amdgcn_mfma_f32_16x16x32_f16(a5, wB[g][q][5], acc[g][q], 0, 0, 0);
#pragma unroll
    for (int g = 0; g < 3; ++g)
#pragma unroll
      for (int q = 0; q < 4; ++q)
        acc[g][q] = __builtin_amdgcn_mfma_f32_16x16x32_f16(a6, wB[g][q][6], acc[g][q], 0, 0, 0);
#pragma unroll
    for (int g = 0; g < 3; ++g)
#pragma unroll
      for (int q = 0; q < 4; ++q)
        acc[g][q] = __builtin_amdgcn_mfma_f32_16x16x32_f16(a7, wB[g][q][7], acc[g][q], 0, 0, 0);

    // ---- epilogue: gates, carry, stores (all in-lane) ----
#pragma unroll
    for (int q = 0; q < 4; ++q) {
      const float r  = sigmoidf_fast(acc[0][q][0] + gcur[q]);
      const float z  = sigmoidf_fast(acc[1][q][0] + gcur[4+q]);
      const float n  = tanhf_fast(gcur[8+q] + r * (acc[2][q][0] + bnq[q]));
      const float hn = (1.f - z) * n + z * hprev[q];
      const float hx = rstn ? 0.f : hn;            // mask BEFORE carry store
      if (lg == 0) yb[(size_t)t * (B_DIM * H_DIM) + 64*w + 16*q + lc] = hn;
      if (lg == 1) hbuf[p ^ 1][64*w + 16*q + lc] = (_Float16)hx;
      hprev[q] = hx;
    }
#pragma unroll
    for (int i = 0; i < 12; ++i) gcur[i] = gnxt[i];

    __syncthreads();   // single barrier per step (double-buffered h)
    p ^= 1;
  }
}

// sentinel: distinctive failure signature if workspace is too small
__global__ void sentinel_kernel(float* out, int n) {
  int i = blockIdx.x * 256 + threadIdx.x;
  if (i < n) out[i] = 12345.0f;
}

// ---------------------------------------------------------------------------
extern "C" void kernel_launch(void* const* d_in, const int* in_sizes, int n_in,
                              void* d_out, int out_size, void* d_ws, size_t ws_size,
                              hipStream_t stream) {
  const float* ins    = (const float*)d_in[0];
  const int*   resets = (const int*)d_in[1];
  const float* h0     = (const float*)d_in[2];
  const float* Wi     = (const float*)d_in[3];
  const float* bi     = (const float*)d_in[4];
  const float* Wh     = (const float*)d_in[5];
  const float* bhn    = (const float*)d_in[6];
  float* ys = (float*)d_out;

  const size_t wbytes  = (size_t)G_DIM * H_DIM * 2;            // 393,216
  const size_t gibytes = (size_t)T_DIM * B_DIM * G_DIM * 2;    // 402,653,184
  const size_t need = 2 * wbytes + gibytes;
  if (ws_size < need) {
    sentinel_kernel<<<(out_size + 255) / 256, 256, 0, stream>>>(ys, out_size);
    return;
  }

  char* ws = (char*)d_ws;
  _Float16* WiT = (_Float16*)ws;
  _Float16* WhT = (_Float16*)(ws + wbytes);
  _Float16* gi  = (_Float16*)(ws + 2 * wbytes);

  prep_kernel<<<(2 * G_DIM * H_DIM) / 256, 256, 0, stream>>>(Wi, Wh, WiT, WhT);

  const int M = T_DIM * B_DIM;                 // 262144
  const int nblocks = (M / BM) * (G_DIM / BN); // 12288
  gemm_gi_kernel<<<nblocks, 256, 0, stream>>>(ins, WiT, bi, gi);

  gru_scan_kernel<<<B_DIM, 256, 0, stream>>>(WhT, gi, resets, h0, bhn, ys);
}

// Round 5
// 2318.330 us; speedup vs baseline: 1.1160x; 1.1160x over previous
//
#include <hip/hip_runtime.h>
#include <hip/hip_fp16.h>

typedef unsigned int u32;
typedef _Float16 half2v __attribute__((ext_vector_type(2)));
typedef _Float16 half4v __attribute__((ext_vector_type(4)));
typedef _Float16 half8v __attribute__((ext_vector_type(8)));
typedef float f32x4 __attribute__((ext_vector_type(4)));

#define T_DIM 1024
#define B_DIM 256
#define H_DIM 256
#define G_DIM 768   // 3*H

// ---------------------------------------------------------------------------
// prep: transpose + f32->f16 for both weight matrices.
// WiT/WhT[g][k] = W[k][g]  (g in [0,768), k in [0,256))
// ---------------------------------------------------------------------------
__global__ void prep_kernel(const float* __restrict__ Wi,
                            const float* __restrict__ Wh,
                            _Float16* __restrict__ WiT,
                            _Float16* __restrict__ WhT) {
  int idx = blockIdx.x * 256 + threadIdx.x;
  const int total = G_DIM * H_DIM;
  const float* src = Wi;
  _Float16* dst = WiT;
  if (idx >= total) { idx -= total; src = Wh; dst = WhT; }
  int g = idx >> 8;     // 0..767
  int k = idx & 255;    // 0..255
  dst[idx] = (_Float16)src[(size_t)k * G_DIM + g];
}

// ---------------------------------------------------------------------------
// Phase 1: gi[M][768] (f16) = ins[M][256] (f32) @ Wi + bi, via MFMA f16.
// (unchanged; secondary target)
// ---------------------------------------------------------------------------
#define BM 128
#define BN 128
#define BK 64
#define LDK 72   // padded f16 leading dim

__global__ __launch_bounds__(256, 2) void gemm_gi_kernel(
    const float* __restrict__ A,       // ins [M][256]
    const _Float16* __restrict__ BT,   // WiT [768][256]
    const float* __restrict__ bias,    // bi [768] f32
    _Float16* __restrict__ C)          // gi [M][768]
{
  __shared__ _Float16 As[BM * LDK];
  __shared__ _Float16 Bs[BN * LDK];

  const int tid  = threadIdx.x;
  const int lane = tid & 63;
  const int wid  = tid >> 6;
  const int wr   = wid >> 1;
  const int wc   = wid & 1;

  const int id   = blockIdx.x;
  const int xcd  = id & 7;
  const int slot = id >> 3;
  const int nt   = slot % 6;
  const int mt   = (slot / 6) * 8 + xcd;
  const int m0 = mt * BM;
  const int n0 = nt * BN;

  f32x4 acc[4][4] = {};

  for (int kt = 0; kt < H_DIM; kt += BK) {
#pragma unroll
    for (int i = 0; i < 8; ++i) {
      int c   = tid + i * 256;
      int row = c >> 4;
      int kc  = (c & 15) << 2;
      const float4 v = *(const float4*)(A + (size_t)(m0 + row) * H_DIM + kt + kc);
      half4v h;
      h.x = (_Float16)v.x; h.y = (_Float16)v.y;
      h.z = (_Float16)v.z; h.w = (_Float16)v.w;
      *(half4v*)(&As[row * LDK + kc]) = h;
    }
#pragma unroll
    for (int i = 0; i < 8; ++i) {
      int c   = tid + i * 256;
      int row = c >> 4;
      int kc  = (c & 15) << 2;
      half4v v = *(const half4v*)(BT + (size_t)(n0 + row) * H_DIM + kt + kc);
      *(half4v*)(&Bs[row * LDK + kc]) = v;
    }
    __syncthreads();

#pragma unroll
    for (int kk = 0; kk < 2; ++kk) {
      half8v af[4], bf[4];
#pragma unroll
      for (int m = 0; m < 4; ++m)
        af[m] = *(const half8v*)(&As[(wr*64 + m*16 + (lane & 15)) * LDK + kk*32 + (lane >> 4)*8]);
#pragma unroll
      for (int n = 0; n < 4; ++n)
        bf[n] = *(const half8v*)(&Bs[(wc*64 + n*16 + (lane & 15)) * LDK + kk*32 + (lane >> 4)*8]);
#pragma unroll
      for (int m = 0; m < 4; ++m)
#pragma unroll
        for (int n = 0; n < 4; ++n)
          acc[m][n] = __builtin_amdgcn_mfma_f32_16x16x32_f16(af[m], bf[n], acc[m][n], 0, 0, 0);
    }
    __syncthreads();
  }

#pragma unroll
  for (int n = 0; n < 4; ++n) {
    const int col = n0 + wc*64 + n*16 + (lane & 15);
    const float bv = bias[col];
#pragma unroll
    for (int m = 0; m < 4; ++m) {
#pragma unroll
      for (int q = 0; q < 4; ++q) {
        const int row = m0 + wr*64 + m*16 + (lane >> 4)*4 + q;
        C[(size_t)row * G_DIM + col] = (_Float16)(acc[m][n][q] + bv);
      }
    }
  }
}

// ---------------------------------------------------------------------------
// Phase 2: MFMA persistent GRU scan, register-dieted.
// 256 blocks (1 chain) x 256 threads (4 waves, 1 wave/SIMD, 512-reg budget).
// Column interleave trick: B-frag tile q covers output cols {64w + 4*lc + q},
// so each thread owns 4 ADJACENT cols -> gi prefetch is 3x8B vector loads
// (12 regs not 24), ys store is one float4, carry store one ds_write_b64.
// Budget: wB 384 (AGPR) + acc 48 + a-stage ~16 + gi 12 + misc ~22 = ~482/512.
// Per step: 8 conflict-free ds_read_b128, 96 MFMA, ~110 VALU, 1 barrier.
// ---------------------------------------------------------------------------
__device__ __forceinline__ float sigmoidf_fast(float x) {
  return __builtin_amdgcn_rcpf(1.f + __expf(-x));
}
__device__ __forceinline__ float tanhf_fast(float x) {
  return 1.f - 2.f * __builtin_amdgcn_rcpf(__expf(2.f * x) + 1.f);
}

#define MFMA_GROUP0(AREG)                                                    \
  _Pragma("unroll")                                                          \
  for (int g = 0; g < 3; ++g)                                                \
    _Pragma("unroll")                                                        \
    for (int q = 0; q < 4; ++q)                                              \
      acc[g][q] = __builtin_amdgcn_mfma_f32_16x16x32_f16(AREG, wB[g][q][0], zero4, 0, 0, 0);

#define MFMA_GROUP(S, AREG)                                                  \
  _Pragma("unroll")                                                          \
  for (int g = 0; g < 3; ++g)                                                \
    _Pragma("unroll")                                                        \
    for (int q = 0; q < 4; ++q)                                              \
      acc[g][q] = __builtin_amdgcn_mfma_f32_16x16x32_f16(AREG, wB[g][q][S], acc[g][q], 0, 0, 0);

__global__ __launch_bounds__(256, 1) void gru_scan_kernel(
    const _Float16* __restrict__ WhT,   // [768][256]
    const _Float16* __restrict__ gi,    // [T][B][768] f16
    const int* __restrict__ resets,     // [T][B] int32
    const float* __restrict__ h0,       // [B][256]
    const float* __restrict__ bhn,      // [256]
    float* __restrict__ ys)             // [T][B][256]
{
  const int b   = blockIdx.x;
  const int tid = threadIdx.x;   // 0..255
  const int w   = tid >> 6;      // wave 0..3
  const int l   = tid & 63;
  const int lg  = l >> 4;        // lane group 0..3 (k sub-slice)
  const int lc  = l & 15;        // lane col slot within tile
  const int c0  = 64*w + 4*lc;   // first of this thread's 4 adjacent cols

  __shared__ __align__(16) _Float16 hbuf[2][H_DIM];

  // ---- persistent B fragments: wB[gate][q][kslice] ----
  // col = 256*g + c0 + q ; k = 32*s + 8*lg + [0..7]
  half8v wB[3][4][8];
#pragma unroll
  for (int g = 0; g < 3; ++g)
#pragma unroll
    for (int q = 0; q < 4; ++q) {
      const _Float16* bp = WhT + (size_t)(256*g + c0 + q) * H_DIM + 8*lg;
#pragma unroll
      for (int s = 0; s < 8; ++s)
        wB[g][q][s] = *(const half8v*)(bp + 32*s);
    }

  const float4 bn4 = *(const float4*)(bhn + c0);

  // ---- init carry (masked by resets[0]) ----
  float hprev[4];
  {
    const int r0 = resets[b];
    const float4 h4 = *(const float4*)(h0 + (size_t)b * H_DIM + c0);
    hprev[0] = r0 ? 0.f : h4.x;
    hprev[1] = r0 ? 0.f : h4.y;
    hprev[2] = r0 ? 0.f : h4.z;
    hprev[3] = r0 ? 0.f : h4.w;
    if (lg == 0) {
      half4v pk;
      pk[0] = (_Float16)hprev[0]; pk[1] = (_Float16)hprev[1];
      pk[2] = (_Float16)hprev[2]; pk[3] = (_Float16)hprev[3];
      *(half4v*)(&hbuf[0][c0]) = pk;
    }
  }
  __syncthreads();

  const _Float16* gbase = gi + (size_t)b * G_DIM;
  float* yb = ys + (size_t)b * H_DIM;

  // preload gi for t=0 (4 adjacent cols per gate = one 8B load each)
  half4v gR = *(const half4v*)(gbase + c0);
  half4v gZ = *(const half4v*)(gbase + 256 + c0);
  half4v gN = *(const half4v*)(gbase + 512 + c0);

  const f32x4 zero4 = {0.f, 0.f, 0.f, 0.f};

  int p = 0;
  for (int t = 0; t < T_DIM; ++t) {
    // ---- prefetch t+1 (clamped; in flight ~1.5 steps) ----
    const int tn = (t + 1 < T_DIM) ? (t + 1) : (T_DIM - 1);
    const _Float16* gp = gbase + (size_t)tn * (B_DIM * G_DIM);
    const half4v gRn = *(const half4v*)(gp + c0);
    const half4v gZn = *(const half4v*)(gp + 256 + c0);
    const half4v gNn = *(const half4v*)(gp + 512 + c0);
    const int rstn = (t + 1 < T_DIM) ? resets[tn * B_DIM + b] : 0;

    // ---- A-frag staged pipeline + 8 MFMA groups (12 MFMA each) ----
    const char* hb = (const char*)(&hbuf[p][0]);
    f32x4 acc[3][4];
    half8v x0 = *(const half8v*)(hb +       16*lg);
    half8v x1 = *(const half8v*)(hb +  64 + 16*lg);
    half8v x2 = *(const half8v*)(hb + 128 + 16*lg);
    MFMA_GROUP0(x0);
    half8v x3 = *(const half8v*)(hb + 192 + 16*lg);
    MFMA_GROUP(1, x1);
    half8v x4 = *(const half8v*)(hb + 256 + 16*lg);
    MFMA_GROUP(2, x2);
    half8v x5 = *(const half8v*)(hb + 320 + 16*lg);
    MFMA_GROUP(3, x3);
    half8v x6 = *(const half8v*)(hb + 384 + 16*lg);
    MFMA_GROUP(4, x4);
    half8v x7 = *(const half8v*)(hb + 448 + 16*lg);
    MFMA_GROUP(5, x5);
    MFMA_GROUP(6, x6);
    MFMA_GROUP(7, x7);

    // ---- epilogue: gates, carry, stores (all in-lane) ----
    float hnv[4];
    half4v pk;
#pragma unroll
    for (int q = 0; q < 4; ++q) {
      const float r  = sigmoidf_fast(acc[0][q][0] + (float)gR[q]);
      const float z  = sigmoidf_fast(acc[1][q][0] + (float)gZ[q]);
      const float bq = (q == 0) ? bn4.x : (q == 1) ? bn4.y : (q == 2) ? bn4.z : bn4.w;
      const float n  = tanhf_fast((float)gN[q] + r * (acc[2][q][0] + bq));
      const float hn = (1.f - z) * n + z * hprev[q];
      const float hx = rstn ? 0.f : hn;        // mask BEFORE carry store
      hnv[q] = hn;
      pk[q] = (_Float16)hx;
      hprev[q] = hx;
    }
    if (lg == 0) {
      float4 o; o.x = hnv[0]; o.y = hnv[1]; o.z = hnv[2]; o.w = hnv[3];
      *(float4*)(yb + (size_t)t * (B_DIM * H_DIM) + c0) = o;
    }
    if (lg == 1) {
      *(half4v*)(&hbuf[p ^ 1][c0]) = pk;
    }
    gR = gRn; gZ = gZn; gN = gNn;

    __syncthreads();   // single barrier per step (double-buffered h)
    p ^= 1;
  }
}

// sentinel: distinctive failure signature if workspace is too small
__global__ void sentinel_kernel(float* out, int n) {
  int i = blockIdx.x * 256 + threadIdx.x;
  if (i < n) out[i] = 12345.0f;
}

// ---------------------------------------------------------------------------
extern "C" void kernel_launch(void* const* d_in, const int* in_sizes, int n_in,
                              void* d_out, int out_size, void* d_ws, size_t ws_size,
                              hipStream_t stream) {
  const float* ins    = (const float*)d_in[0];
  const int*   resets = (const int*)d_in[1];
  const float* h0     = (const float*)d_in[2];
  const float* Wi     = (const float*)d_in[3];
  const float* bi     = (const float*)d_in[4];
  const float* Wh     = (const float*)d_in[5];
  const float* bhn    = (const float*)d_in[6];
  float* ys = (float*)d_out;

  const size_t wbytes  = (size_t)G_DIM * H_DIM * 2;            // 393,216
  const size_t gibytes = (size_t)T_DIM * B_DIM * G_DIM * 2;    // 402,653,184
  const size_t need = 2 * wbytes + gibytes;
  if (ws_size < need) {
    sentinel_kernel<<<(out_size + 255) / 256, 256, 0, stream>>>(ys, out_size);
    return;
  }

  char* ws = (char*)d_ws;
  _Float16* WiT = (_Float16*)ws;
  _Float16* WhT = (_Float16*)(ws + wbytes);
  _Float16* gi  = (_Float16*)(ws + 2 * wbytes);

  prep_kernel<<<(2 * G_DIM * H_DIM) / 256, 256, 0, stream>>>(Wi, Wh, WiT, WhT);

  const int M = T_DIM * B_DIM;                 // 262144
  const int nblocks = (M / BM) * (G_DIM / BN); // 12288
  gemm_gi_kernel<<<nblocks, 256, 0, stream>>>(ins, WiT, bi, gi);

  gru_scan_kernel<<<B_DIM, 256, 0, stream>>>(WhT, gi, resets, h0, bhn, ys);
}

// Round 6
// 1851.865 us; speedup vs baseline: 1.3971x; 1.2519x over previous
//
#include <hip/hip_runtime.h>
#include <hip/hip_fp16.h>

typedef unsigned int u32;
typedef _Float16 half2v __attribute__((ext_vector_type(2)));
typedef _Float16 half4v __attribute__((ext_vector_type(4)));
typedef _Float16 half8v __attribute__((ext_vector_type(8)));
typedef float f32x4 __attribute__((ext_vector_type(4)));

#define T_DIM 1024
#define B_DIM 256
#define H_DIM 256
#define G_DIM 768   // 3*H

// ---------------------------------------------------------------------------
// prep: transpose + f32->f16 for both weight matrices.
// ---------------------------------------------------------------------------
__global__ void prep_kernel(const float* __restrict__ Wi,
                            const float* __restrict__ Wh,
                            _Float16* __restrict__ WiT,
                            _Float16* __restrict__ WhT) {
  int idx = blockIdx.x * 256 + threadIdx.x;
  const int total = G_DIM * H_DIM;
  const float* src = Wi;
  _Float16* dst = WiT;
  if (idx >= total) { idx -= total; src = Wh; dst = WhT; }
  int g = idx >> 8;     // 0..767
  int k = idx & 255;    // 0..255
  dst[idx] = (_Float16)src[(size_t)k * G_DIM + g];
}

// ---------------------------------------------------------------------------
// Phase 1: gi[M][768] (f16) = ins[M][256] (f32) @ Wi + bi, via MFMA f16.
// (unchanged; secondary target)
// ---------------------------------------------------------------------------
#define BM 128
#define BN 128
#define BK 64
#define LDK 72   // padded f16 leading dim

__global__ __launch_bounds__(256, 2) void gemm_gi_kernel(
    const float* __restrict__ A,       // ins [M][256]
    const _Float16* __restrict__ BT,   // WiT [768][256]
    const float* __restrict__ bias,    // bi [768] f32
    _Float16* __restrict__ C)          // gi [M][768]
{
  __shared__ _Float16 As[BM * LDK];
  __shared__ _Float16 Bs[BN * LDK];

  const int tid  = threadIdx.x;
  const int lane = tid & 63;
  const int wid  = tid >> 6;
  const int wr   = wid >> 1;
  const int wc   = wid & 1;

  const int id   = blockIdx.x;
  const int xcd  = id & 7;
  const int slot = id >> 3;
  const int nt   = slot % 6;
  const int mt   = (slot / 6) * 8 + xcd;
  const int m0 = mt * BM;
  const int n0 = nt * BN;

  f32x4 acc[4][4] = {};

  for (int kt = 0; kt < H_DIM; kt += BK) {
#pragma unroll
    for (int i = 0; i < 8; ++i) {
      int c   = tid + i * 256;
      int row = c >> 4;
      int kc  = (c & 15) << 2;
      const float4 v = *(const float4*)(A + (size_t)(m0 + row) * H_DIM + kt + kc);
      half4v h;
      h.x = (_Float16)v.x; h.y = (_Float16)v.y;
      h.z = (_Float16)v.z; h.w = (_Float16)v.w;
      *(half4v*)(&As[row * LDK + kc]) = h;
    }
#pragma unroll
    for (int i = 0; i < 8; ++i) {
      int c   = tid + i * 256;
      int row = c >> 4;
      int kc  = (c & 15) << 2;
      half4v v = *(const half4v*)(BT + (size_t)(n0 + row) * H_DIM + kt + kc);
      *(half4v*)(&Bs[row * LDK + kc]) = v;
    }
    __syncthreads();

#pragma unroll
    for (int kk = 0; kk < 2; ++kk) {
      half8v af[4], bf[4];
#pragma unroll
      for (int m = 0; m < 4; ++m)
        af[m] = *(const half8v*)(&As[(wr*64 + m*16 + (lane & 15)) * LDK + kk*32 + (lane >> 4)*8]);
#pragma unroll
      for (int n = 0; n < 4; ++n)
        bf[n] = *(const half8v*)(&Bs[(wc*64 + n*16 + (lane & 15)) * LDK + kk*32 + (lane >> 4)*8]);
#pragma unroll
      for (int m = 0; m < 4; ++m)
#pragma unroll
        for (int n = 0; n < 4; ++n)
          acc[m][n] = __builtin_amdgcn_mfma_f32_16x16x32_f16(af[m], bf[n], acc[m][n], 0, 0, 0);
    }
    __syncthreads();
  }

#pragma unroll
  for (int n = 0; n < 4; ++n) {
    const int col = n0 + wc*64 + n*16 + (lane & 15);
    const float bv = bias[col];
#pragma unroll
    for (int m = 0; m < 4; ++m) {
#pragma unroll
      for (int q = 0; q < 4; ++q) {
        const int row = m0 + wr*64 + m*16 + (lane >> 4)*4 + q;
        C[(size_t)row * G_DIM + col] = (_Float16)(acc[m][n][q] + bv);
      }
    }
  }
}

// ---------------------------------------------------------------------------
// Phase 2: MFMA persistent GRU scan — inline-asm MFMA with explicit register
// classes. 256 blocks x 256 threads (4 waves, 1 wave/SIMD, 512-reg unified).
// Class partition (the round-5 fix): gates r,z weights (64 quads = 256 regs)
// pinned to AGPR via "a" constraints — MFMA reads B from AGPR NATIVELY, no
// accvgpr_read copies (round 5 burned ~384 VALU/step on those). Gate n
// weights (128), acc (48), A-frags (32), gi (12) on the VGPR side (~250/256).
// Hazards: compiler can't see asm is MFMA, so MFMA-dst -> VALU-read gets
// sched_barrier + 2x s_nop 7 before the epilogue. No register reuse inside
// a step -> no WAR windows.
// ---------------------------------------------------------------------------
__device__ __forceinline__ float sigmoidf_fast(float x) {
  return __builtin_amdgcn_rcpf(1.f + __expf(-x));
}
__device__ __forceinline__ float tanhf_fast(float x) {
  return 1.f - 2.f * __builtin_amdgcn_rcpf(__expf(2.f * x) + 1.f);
}

// B in AGPR ("a"), first k-slice (C = persistent zero quad, fresh dst)
__device__ __forceinline__ f32x4 mfma_az(half8v a, half8v b, f32x4 z) {
  f32x4 d;
  asm("v_mfma_f32_16x16x32_f16 %0, %1, %2, %3"
      : "=&v"(d) : "v"(a), "a"(b), "v"(z));
  return d;
}
// B in AGPR, accumulate in place
__device__ __forceinline__ void mfma_aa(half8v a, half8v b, f32x4& c) {
  asm("v_mfma_f32_16x16x32_f16 %0, %1, %2, %0"
      : "+v"(c) : "v"(a), "a"(b));
}
// B in VGPR, first k-slice
__device__ __forceinline__ f32x4 mfma_vz(half8v a, half8v b, f32x4 z) {
  f32x4 d;
  asm("v_mfma_f32_16x16x32_f16 %0, %1, %2, %3"
      : "=&v"(d) : "v"(a), "v"(b), "v"(z));
  return d;
}
// B in VGPR, accumulate in place
__device__ __forceinline__ void mfma_va(half8v a, half8v b, f32x4& c) {
  asm("v_mfma_f32_16x16x32_f16 %0, %1, %2, %0"
      : "+v"(c) : "v"(a), "v"(b));
}

#define MFMA_GROUP0(X)                                                       \
  _Pragma("unroll")                                                          \
  for (int q = 0; q < 4; ++q) accR[q] = mfma_az(X, wR[q][0], zero4);         \
  _Pragma("unroll")                                                          \
  for (int q = 0; q < 4; ++q) accZ[q] = mfma_az(X, wZ[q][0], zero4);         \
  _Pragma("unroll")                                                          \
  for (int q = 0; q < 4; ++q) accN[q] = mfma_vz(X, wN[q][0], zero4);

#define MFMA_GROUP(S, X)                                                     \
  _Pragma("unroll")                                                          \
  for (int q = 0; q < 4; ++q) mfma_aa(X, wR[q][S], accR[q]);                 \
  _Pragma("unroll")                                                          \
  for (int q = 0; q < 4; ++q) mfma_aa(X, wZ[q][S], accZ[q]);                 \
  _Pragma("unroll")                                                          \
  for (int q = 0; q < 4; ++q) mfma_va(X, wN[q][S], accN[q]);

__global__ __launch_bounds__(256, 1) void gru_scan_kernel(
    const _Float16* __restrict__ WhT,   // [768][256]
    const _Float16* __restrict__ gi,    // [T][B][768] f16
    const int* __restrict__ resets,     // [T][B] int32
    const float* __restrict__ h0,       // [B][256]
    const float* __restrict__ bhn,      // [256]
    float* __restrict__ ys)             // [T][B][256]
{
  const int b   = blockIdx.x;
  const int tid = threadIdx.x;   // 0..255
  const int w   = tid >> 6;      // wave 0..3
  const int l   = tid & 63;
  const int lg  = l >> 4;        // lane group 0..3 (k sub-slice)
  const int lc  = l & 15;        // lane col slot within tile
  const int c0  = 64*w + 4*lc;   // first of this thread's 4 adjacent cols

  __shared__ __align__(16) _Float16 hbuf[2][H_DIM];

  // ---- persistent B fragments ----
  // col = 256*g + c0 + q ; k = 32*s + 8*lg + [0..7]
  // wR,wZ -> AGPR (via "a" asm uses); wN -> VGPR.
  half8v wR[4][8], wZ[4][8], wN[4][8];
#pragma unroll
  for (int q = 0; q < 4; ++q) {
    const _Float16* bp = WhT + (size_t)(c0 + q) * H_DIM + 8*lg;
#pragma unroll
    for (int s = 0; s < 8; ++s) wR[q][s] = *(const half8v*)(bp + 32*s);
  }
#pragma unroll
  for (int q = 0; q < 4; ++q) {
    const _Float16* bp = WhT + (size_t)(256 + c0 + q) * H_DIM + 8*lg;
#pragma unroll
    for (int s = 0; s < 8; ++s) wZ[q][s] = *(const half8v*)(bp + 32*s);
  }
#pragma unroll
  for (int q = 0; q < 4; ++q) {
    const _Float16* bp = WhT + (size_t)(512 + c0 + q) * H_DIM + 8*lg;
#pragma unroll
    for (int s = 0; s < 8; ++s) wN[q][s] = *(const half8v*)(bp + 32*s);
  }

  const float4 bn4 = *(const float4*)(bhn + c0);

  // ---- init carry (masked by resets[0]) ----
  float hprev[4];
  {
    const int r0 = resets[b];
    const float4 h4 = *(const float4*)(h0 + (size_t)b * H_DIM + c0);
    hprev[0] = r0 ? 0.f : h4.x;
    hprev[1] = r0 ? 0.f : h4.y;
    hprev[2] = r0 ? 0.f : h4.z;
    hprev[3] = r0 ? 0.f : h4.w;
    if (lg == 0) {
      half4v pk;
      pk[0] = (_Float16)hprev[0]; pk[1] = (_Float16)hprev[1];
      pk[2] = (_Float16)hprev[2]; pk[3] = (_Float16)hprev[3];
      *(half4v*)(&hbuf[0][c0]) = pk;
    }
  }
  __syncthreads();

  const _Float16* gbase = gi + (size_t)b * G_DIM;
  float* yb = ys + (size_t)b * H_DIM;

  // preload gi for t=0
  half4v gR = *(const half4v*)(gbase + c0);
  half4v gZ = *(const half4v*)(gbase + 256 + c0);
  half4v gN = *(const half4v*)(gbase + 512 + c0);

  const f32x4 zero4 = {0.f, 0.f, 0.f, 0.f};

  int p = 0;
  for (int t = 0; t < T_DIM; ++t) {
    // ---- prefetch t+1 (clamped) ----
    const int tn = (t + 1 < T_DIM) ? (t + 1) : (T_DIM - 1);
    const _Float16* gp = gbase + (size_t)tn * (B_DIM * G_DIM);
    const half4v gRn = *(const half4v*)(gp + c0);
    const half4v gZn = *(const half4v*)(gp + 256 + c0);
    const half4v gNn = *(const half4v*)(gp + 512 + c0);
    const int rstn = (t + 1 < T_DIM) ? resets[tn * B_DIM + b] : 0;

    // ---- A-frags (all 8 up front; no reuse -> no WAR hazard windows) ----
    const char* hb = (const char*)(&hbuf[p][0]);
    half8v x0 = *(const half8v*)(hb +       16*lg);
    half8v x1 = *(const half8v*)(hb +  64 + 16*lg);
    half8v x2 = *(const half8v*)(hb + 128 + 16*lg);
    half8v x3 = *(const half8v*)(hb + 192 + 16*lg);
    half8v x4 = *(const half8v*)(hb + 256 + 16*lg);
    half8v x5 = *(const half8v*)(hb + 320 + 16*lg);
    half8v x6 = *(const half8v*)(hb + 384 + 16*lg);
    half8v x7 = *(const half8v*)(hb + 448 + 16*lg);

    f32x4 accR[4], accZ[4], accN[4];
    MFMA_GROUP0(x0);
    MFMA_GROUP(1, x1);
    MFMA_GROUP(2, x2);
    MFMA_GROUP(3, x3);
    MFMA_GROUP(4, x4);
    MFMA_GROUP(5, x5);
    MFMA_GROUP(6, x6);
    MFMA_GROUP(7, x7);

    // MFMA dst -> VALU read hazard fence (compiler can't see asm is MFMA)
    __builtin_amdgcn_sched_barrier(0);
    asm volatile("s_nop 7\n\ts_nop 7" ::: );
    __builtin_amdgcn_sched_barrier(0);

    // ---- epilogue: gates, carry, stores (all in-lane) ----
    float hnv[4];
    half4v pk;
#pragma unroll
    for (int q = 0; q < 4; ++q) {
      const float r  = sigmoidf_fast(accR[q][0] + (float)gR[q]);
      const float z  = sigmoidf_fast(accZ[q][0] + (float)gZ[q]);
      const float bq = (q == 0) ? bn4.x : (q == 1) ? bn4.y : (q == 2) ? bn4.z : bn4.w;
      const float n  = tanhf_fast((float)gN[q] + r * (accN[q][0] + bq));
      const float hn = (1.f - z) * n + z * hprev[q];
      const float hx = rstn ? 0.f : hn;        // mask BEFORE carry store
      hnv[q] = hn;
      pk[q] = (_Float16)hx;
      hprev[q] = hx;
    }
    if (lg == 0) {
      float4 o; o.x = hnv[0]; o.y = hnv[1]; o.z = hnv[2]; o.w = hnv[3];
      *(float4*)(yb + (size_t)t * (B_DIM * H_DIM) + c0) = o;
    }
    if (lg == 1) {
      *(half4v*)(&hbuf[p ^ 1][c0]) = pk;
    }
    gR = gRn; gZ = gZn; gN = gNn;

    __syncthreads();   // single barrier per step (double-buffered h)
    p ^= 1;
  }
}

// sentinel: distinctive failure signature if workspace is too small
__global__ void sentinel_kernel(float* out, int n) {
  int i = blockIdx.x * 256 + threadIdx.x;
  if (i < n) out[i] = 12345.0f;
}

// ---------------------------------------------------------------------------
extern "C" void kernel_launch(void* const* d_in, const int* in_sizes, int n_in,
                              void* d_out, int out_size, void* d_ws, size_t ws_size,
                              hipStream_t stream) {
  const float* ins    = (const float*)d_in[0];
  const int*   resets = (const int*)d_in[1];
  const float* h0     = (const float*)d_in[2];
  const float* Wi     = (const float*)d_in[3];
  const float* bi     = (const float*)d_in[4];
  const float* Wh     = (const float*)d_in[5];
  const float* bhn    = (const float*)d_in[6];
  float* ys = (float*)d_out;

  const size_t wbytes  = (size_t)G_DIM * H_DIM * 2;            // 393,216
  const size_t gibytes = (size_t)T_DIM * B_DIM * G_DIM * 2;    // 402,653,184
  const size_t need = 2 * wbytes + gibytes;
  if (ws_size < need) {
    sentinel_kernel<<<(out_size + 255) / 256, 256, 0, stream>>>(ys, out_size);
    return;
  }

  char* ws = (char*)d_ws;
  _Float16* WiT = (_Float16*)ws;
  _Float16* WhT = (_Float16*)(ws + wbytes);
  _Float16* gi  = (_Float16*)(ws + 2 * wbytes);

  prep_kernel<<<(2 * G_DIM * H_DIM) / 256, 256, 0, stream>>>(Wi, Wh, WiT, WhT);

  const int M = T_DIM * B_DIM;                 // 262144
  const int nblocks = (M / BM) * (G_DIM / BN); // 12288
  gemm_gi_kernel<<<nblocks, 256, 0, stream>>>(ins, WiT, bi, gi);

  gru_scan_kernel<<<B_DIM, 256, 0, stream>>>(WhT, gi, resets, h0, bhn, ys);
}